// Round 10
// baseline (445.088 us; speedup 1.0000x reference)
//
#include <hip/hip_runtime.h>
#include <math.h>

#define HID 36
#define NH 3
#define HD 12
#define BSHIFT 13   // src-bucket = src >> 13 (locality ordering in lists)
#define NBUCK 13
#define PSHIFT 8    // dst partition = dst >> 8 (256 dsts per partition)
#define PCHUNK 8192 // edges per chunk in partition pass

typedef _Float16 f16;
typedef unsigned short u16;

// ---------------- CSR build: atomic-free two-level partition sort ----------

__global__ void hist2_kernel(const int* __restrict__ dst, int* __restrict__ M,
                             int E, int C, int np) {
    __shared__ int h[512];
    int t = threadIdx.x;
    int c = blockIdx.x;
    for (int i = t; i < 512; i += blockDim.x) h[i] = 0;
    __syncthreads();
    int i0 = c * PCHUNK;
    int i1 = min(i0 + PCHUNK, E);
    for (int i = i0 + t; i < i1; i += blockDim.x)
        atomicAdd(&h[dst[i] >> PSHIFT], 1);
    __syncthreads();
    for (int b = t; b < np; b += blockDim.x)
        M[(size_t)b * C + c] = h[b];
}

__global__ void base_scan_kernel(const int* __restrict__ M, int* __restrict__ BaseT,
                                 int* __restrict__ T, int C, int np) {
    __shared__ int tmp[512];
    int b = blockIdx.x;
    int t = threadIdx.x;
    int v = (t < C) ? M[(size_t)b * C + t] : 0;
    tmp[t] = v;
    __syncthreads();
    for (int ofs = 1; ofs < 512; ofs <<= 1) {
        int x = 0;
        if (t >= ofs) x = tmp[t - ofs];
        __syncthreads();
        tmp[t] += x;
        __syncthreads();
    }
    if (t < C) BaseT[(size_t)t * 512 + b] = tmp[t] - v;
    if (t == 511) T[b] = tmp[511];
}

__global__ void scan_small_kernel(const int* __restrict__ T, int* __restrict__ poff, int np) {
    __shared__ int tmp[512];
    int t = threadIdx.x;
    int v = (t < np) ? T[t] : 0;
    tmp[t] = v;
    __syncthreads();
    for (int ofs = 1; ofs < 512; ofs <<= 1) {
        int x = 0;
        if (t >= ofs) x = tmp[t - ofs];
        __syncthreads();
        tmp[t] += x;
        __syncthreads();
    }
    int excl = tmp[t] - v;
    if (t < np) poff[t] = excl;
    if (t == np - 1) poff[np] = excl + v;
}

__global__ void part_scatter_kernel(const int* __restrict__ src, const int* __restrict__ dst,
                                    const int* __restrict__ BaseT, const int* __restrict__ poff,
                                    int* __restrict__ part, int E, int np) {
    __shared__ int h[512];
    __shared__ int base[512];
    int t = threadIdx.x;
    int c = blockIdx.x;
    for (int i = t; i < 512; i += blockDim.x) h[i] = 0;
    for (int b = t; b < np; b += blockDim.x)
        base[b] = poff[b] + BaseT[(size_t)c * 512 + b];
    __syncthreads();
    int i0 = c * PCHUNK;
    int i1 = min(i0 + PCHUNK, E);
    for (int i = i0 + t; i < i1; i += blockDim.x) {
        int d = dst[i];
        int bin = d >> PSHIFT;
        int r = atomicAdd(&h[bin], 1);
        part[base[bin] + r] = (src[i] << PSHIFT) | (d & ((1 << PSHIFT) - 1));
    }
}

// one block per partition: LDS counting sort by (dst_local, src_bucket).
// csr entries = src*48 (f16-element offset of the packed row).
__global__ void bucket_csr_kernel(const int* __restrict__ part, const int* __restrict__ T,
                                  const int* __restrict__ poff,
                                  int* __restrict__ csr, int* __restrict__ off,
                                  int n, int E) {
    __shared__ int cnt[256 * NBUCK];
    __shared__ int psum[256];
    int p = blockIdx.x;
    int t = threadIdx.x;
    int dbase = p << PSHIFT;
    int nd = min(256, n - dbase);
    int nc = nd * NBUCK;
    for (int i = t; i < nc; i += blockDim.x) cnt[i] = 0;
    __syncthreads();
    int cnt_p = T[p];
    int e0 = poff[p];
    const int* pp = part + e0;
    for (int i = t; i < cnt_p; i += blockDim.x) {
        int e = pp[i];
        atomicAdd(&cnt[(e & 255) * NBUCK + ((e >> PSHIFT) >> BSHIFT)], 1);
    }
    __syncthreads();
    int sum = 0;
    if (t < nd) {
        for (int k = 0; k < NBUCK; ++k) {
            int c = cnt[t * NBUCK + k];
            cnt[t * NBUCK + k] = sum;
            sum += c;
        }
    }
    psum[t] = (t < nd) ? sum : 0;
    __syncthreads();
    for (int ofs = 1; ofs < 256; ofs <<= 1) {
        int x = 0;
        if (t >= ofs) x = psum[t - ofs];
        __syncthreads();
        psum[t] += x;
        __syncthreads();
    }
    int dexcl = (t > 0) ? psum[t - 1] : 0;
    int start = e0 + dexcl;
    if (t < nd) {
        for (int k = 0; k < NBUCK; ++k) cnt[t * NBUCK + k] += start;
        off[dbase + t] = start;
    }
    __syncthreads();
    for (int i = t; i < cnt_p; i += blockDim.x) {
        int e = pp[i];
        int s = e >> PSHIFT;
        int idx = (e & 255) * NBUCK + (s >> BSHIFT);
        int pos = atomicAdd(&cnt[idx], 1);
        csr[pos] = s * 48;
    }
    if (p == 0 && t == 0) off[n] = E;
}

// ---------------- fused node kernels ----------------

__device__ __forceinline__ void edge_accum(uint4 qa, uint4 qb, float ern,
                                           float& denom, float* acc) {
    union { uint4 q[2]; f16 hx[16]; } v;
    v.q[0] = qa;
    v.q[1] = qb;
    float e = (float)v.hx[12] + ern;
    e = (e >= 0.f) ? e : 0.2f * e;
    float w = __expf(e);
    denom += w;
#pragma unroll
    for (int k = 0; k < HD; ++k) acc[k] += w * (float)v.hx[k];
}

// h0 = x@W0+b0 ; feat = h0@FCW ; pack {feat12,el}x3 + er  (two reg-GEMMs)
__global__ void lin0tr_kernel(const float* __restrict__ x, const float* __restrict__ w0,
                              const float* __restrict__ b0, const float* __restrict__ fcw,
                              const float* __restrict__ al, const float* __restrict__ ar,
                              float* __restrict__ h, f16* __restrict__ packed,
                              float* __restrict__ er, int n) {
    __shared__ float W0[HID * HID];
    __shared__ float W1[HID * HID];
    __shared__ float Bs[HID], ALs[HID], ARs[HID];
    int t = threadIdx.x;
    for (int i = t; i < HID * HID; i += 256) { W0[i] = w0[i]; W1[i] = fcw[i]; }
    if (t < HID) { Bs[t] = b0[t]; ALs[t] = al[t]; ARs[t] = ar[t]; }
    __syncthreads();
    int node = blockIdx.x * 256 + t;
    if (node >= n) return;
    const float4* xp = (const float4*)(x + (size_t)node * HID);
    float h0[HID];
#pragma unroll
    for (int j = 0; j < HID; ++j) h0[j] = Bs[j];
#pragma unroll
    for (int kk = 0; kk < HID / 4; ++kk) {
        float4 xv = xp[kk];
        const float* w = &W0[(4 * kk) * HID];
#pragma unroll
        for (int j = 0; j < HID; ++j)
            h0[j] += xv.x * w[j] + xv.y * w[HID + j] + xv.z * w[2 * HID + j] + xv.w * w[3 * HID + j];
    }
    float* hp = h + (size_t)node * HID;
#pragma unroll
    for (int j = 0; j < HID; ++j) hp[j] = h0[j];
    float feat[HID];
#pragma unroll
    for (int j = 0; j < HID; ++j) feat[j] = 0.f;
#pragma unroll
    for (int k = 0; k < HID; ++k) {
        float hv = h0[k];
        const float* w = &W1[k * HID];
#pragma unroll
        for (int j = 0; j < HID; ++j) feat[j] += hv * w[j];
    }
    union { f16 hx[48]; uint4 q[6]; } u;
#pragma unroll
    for (int hh = 0; hh < NH; ++hh) {
        float sl = 0.f, sr = 0.f;
#pragma unroll
        for (int d = 0; d < HD; ++d) {
            sl += feat[hh * HD + d] * ALs[hh * HD + d];
            sr += feat[hh * HD + d] * ARs[hh * HD + d];
        }
#pragma unroll
        for (int d = 0; d < HD; ++d) u.hx[hh * 16 + d] = (f16)feat[hh * HD + d];
        u.hx[hh * 16 + 12] = (f16)sl;
        u.hx[hh * 16 + 13] = (f16)0.f;
        u.hx[hh * 16 + 14] = (f16)0.f;
        u.hx[hh * 16 + 15] = (f16)0.f;
        er[node * NH + hh] = sr;
    }
    uint4* prow = (uint4*)(packed + (size_t)node * 48);
#pragma unroll
    for (int q = 0; q < 6; ++q) prow[q] = u.q[q];
}

// fused: aggregate(layer l) -> hnext, then transform(layer l+1) via LDS
// exchange. 192 threads = 64 nodes x 3 heads. Edge loop unrolled x4 with
// batched loads -> 4 independent gather chains per lane in flight.
__global__ void __launch_bounds__(192)
aggtr_kernel(const f16* __restrict__ packed_in, const float* __restrict__ er_in,
             const float* __restrict__ hcur, const int* __restrict__ off,
             const int* __restrict__ csr, const float* __restrict__ bias,
             const float* __restrict__ wnext, const float* __restrict__ aln,
             const float* __restrict__ arn, float* __restrict__ hnext,
             f16* __restrict__ packed_out, float* __restrict__ er_out, int n) {
    __shared__ float Wsh[HID * HID];
    __shared__ float ALs[HID], ARs[HID];
    __shared__ float hsh[64 * 37];
    int t = threadIdx.x;
    for (int i = t; i < HID * HID; i += 192) Wsh[i] = wnext[i];
    if (t < HID) { ALs[t] = aln[t]; ARs[t] = arn[t]; }
    int ln = t / 3, hh = t - ln * 3;
    int node = blockIdx.x * 64 + ln;
    bool active = (node < n);
    int j = 0, len = 0;
    float ern = 0.f;
    if (active) {
        j = off[node];
        len = off[node + 1] - j;
        ern = er_in[node * NH + hh];
    }
    const f16* pb = packed_in + hh * 16;

    float denom = 0.f;
    float acc[HD];
#pragma unroll
    for (int k = 0; k < HD; ++k) acc[k] = 0.f;

    for (; len >= 4; len -= 4, j += 4) {
        int o0 = csr[j], o1 = csr[j + 1], o2 = csr[j + 2], o3 = csr[j + 3];
        const uint4* r0 = (const uint4*)(pb + o0);
        const uint4* r1 = (const uint4*)(pb + o1);
        const uint4* r2 = (const uint4*)(pb + o2);
        const uint4* r3 = (const uint4*)(pb + o3);
        uint4 a0 = r0[0], b0 = r0[1];
        uint4 a1 = r1[0], b1 = r1[1];
        uint4 a2 = r2[0], b2 = r2[1];
        uint4 a3 = r3[0], b3 = r3[1];
        edge_accum(a0, b0, ern, denom, acc);
        edge_accum(a1, b1, ern, denom, acc);
        edge_accum(a2, b2, ern, denom, acc);
        edge_accum(a3, b3, ern, denom, acc);
    }
    for (; len > 0; --len, ++j) {
        int o = csr[j];
        const uint4* r = (const uint4*)(pb + o);
        edge_accum(r[0], r[1], ern, denom, acc);
    }

    // epilogue: hnext = elu(acc/denom + hcur + bias)
    float v[HD];
#pragma unroll
    for (int k = 0; k < HD; ++k) v[k] = 0.f;
    if (active) {
        float inv = 1.f / fmaxf(denom, 1e-9f);
        int base = node * HID + hh * HD;
        const float4* hc = (const float4*)(hcur + base);
        float4 h0 = hc[0], h1 = hc[1], h2 = hc[2];
        float hres[HD] = {h0.x, h0.y, h0.z, h0.w, h1.x, h1.y, h1.z, h1.w, h2.x, h2.y, h2.z, h2.w};
#pragma unroll
        for (int k = 0; k < HD; ++k) {
            float x = acc[k] * inv + hres[k] + bias[hh * HD + k];
            v[k] = (x > 0.f) ? x : expm1f(x);
        }
        float4* hp = (float4*)(hnext + base);
        hp[0] = make_float4(v[0], v[1], v[2], v[3]);
        hp[1] = make_float4(v[4], v[5], v[6], v[7]);
        hp[2] = make_float4(v[8], v[9], v[10], v[11]);
    }
#pragma unroll
    for (int k = 0; k < HD; ++k) hsh[ln * 37 + hh * HD + k] = v[k];
    __syncthreads();

    // transform tail: feat12 = hsh[ln][:] @ Wsh[:, hh*12..], then el/er+pack
    float feat[HD];
#pragma unroll
    for (int d = 0; d < HD; ++d) feat[d] = 0.f;
    const float* hrow = &hsh[ln * 37];
#pragma unroll 4
    for (int k = 0; k < HID; ++k) {
        float hv = hrow[k];
        const float* w = &Wsh[k * HID + hh * HD];
#pragma unroll
        for (int d = 0; d < HD; ++d) feat[d] += hv * w[d];
    }
    if (!active) return;
    float sl = 0.f, sr = 0.f;
#pragma unroll
    for (int d = 0; d < HD; ++d) {
        sl += feat[d] * ALs[hh * HD + d];
        sr += feat[d] * ARs[hh * HD + d];
    }
    union { f16 hx[16]; uint4 q[2]; } o;
#pragma unroll
    for (int d = 0; d < HD; ++d) o.hx[d] = (f16)feat[d];
    o.hx[12] = (f16)sl;
    o.hx[13] = (f16)0.f; o.hx[14] = (f16)0.f; o.hx[15] = (f16)0.f;
    uint4* prow = (uint4*)(packed_out + (size_t)node * 48 + hh * 16);
    prow[0] = o.q[0];
    prow[1] = o.q[1];
    er_out[node * NH + hh] = sr;
}

// fused: aggregate(last layer) -> h3 (in-reg) -> out = h3@OW + ob
__global__ void __launch_bounds__(192)
aggout_kernel(const f16* __restrict__ packed_in, const float* __restrict__ er_in,
              const float* __restrict__ hcur, const int* __restrict__ off,
              const int* __restrict__ csr, const float* __restrict__ bias,
              const float* __restrict__ ow, const float* __restrict__ ob,
              float* __restrict__ out, int n) {
    __shared__ float Wsh[HID * HID];
    __shared__ float OBs[HID];
    __shared__ float hsh[64 * 37];
    int t = threadIdx.x;
    for (int i = t; i < HID * HID; i += 192) Wsh[i] = ow[i];
    if (t < HID) OBs[t] = ob[t];
    int ln = t / 3, hh = t - ln * 3;
    int node = blockIdx.x * 64 + ln;
    bool active = (node < n);
    int j = 0, len = 0;
    float ern = 0.f;
    if (active) {
        j = off[node];
        len = off[node + 1] - j;
        ern = er_in[node * NH + hh];
    }
    const f16* pb = packed_in + hh * 16;

    float denom = 0.f;
    float acc[HD];
#pragma unroll
    for (int k = 0; k < HD; ++k) acc[k] = 0.f;

    for (; len >= 4; len -= 4, j += 4) {
        int o0 = csr[j], o1 = csr[j + 1], o2 = csr[j + 2], o3 = csr[j + 3];
        const uint4* r0 = (const uint4*)(pb + o0);
        const uint4* r1 = (const uint4*)(pb + o1);
        const uint4* r2 = (const uint4*)(pb + o2);
        const uint4* r3 = (const uint4*)(pb + o3);
        uint4 a0 = r0[0], b0 = r0[1];
        uint4 a1 = r1[0], b1 = r1[1];
        uint4 a2 = r2[0], b2 = r2[1];
        uint4 a3 = r3[0], b3 = r3[1];
        edge_accum(a0, b0, ern, denom, acc);
        edge_accum(a1, b1, ern, denom, acc);
        edge_accum(a2, b2, ern, denom, acc);
        edge_accum(a3, b3, ern, denom, acc);
    }
    for (; len > 0; --len, ++j) {
        int o = csr[j];
        const uint4* r = (const uint4*)(pb + o);
        edge_accum(r[0], r[1], ern, denom, acc);
    }

    float v[HD];
#pragma unroll
    for (int k = 0; k < HD; ++k) v[k] = 0.f;
    if (active) {
        float inv = 1.f / fmaxf(denom, 1e-9f);
        int base = node * HID + hh * HD;
        const float4* hc = (const float4*)(hcur + base);
        float4 h0 = hc[0], h1 = hc[1], h2 = hc[2];
        float hres[HD] = {h0.x, h0.y, h0.z, h0.w, h1.x, h1.y, h1.z, h1.w, h2.x, h2.y, h2.z, h2.w};
#pragma unroll
        for (int k = 0; k < HD; ++k) {
            float x = acc[k] * inv + hres[k] + bias[hh * HD + k];
            v[k] = (x > 0.f) ? x : expm1f(x);
        }
    }
#pragma unroll
    for (int k = 0; k < HD; ++k) hsh[ln * 37 + hh * HD + k] = v[k];
    __syncthreads();

    float feat[HD];
#pragma unroll
    for (int d = 0; d < HD; ++d) feat[d] = OBs[hh * HD + d];
    const float* hrow = &hsh[ln * 37];
#pragma unroll 4
    for (int k = 0; k < HID; ++k) {
        float hv = hrow[k];
        const float* w = &Wsh[k * HID + hh * HD];
#pragma unroll
        for (int d = 0; d < HD; ++d) feat[d] += hv * w[d];
    }
    if (!active) return;
    float4* op = (float4*)(out + (size_t)node * HID + hh * HD);
    op[0] = make_float4(feat[0], feat[1], feat[2], feat[3]);
    op[1] = make_float4(feat[4], feat[5], feat[6], feat[7]);
    op[2] = make_float4(feat[8], feat[9], feat[10], feat[11]);
}

// ---------------- launch ----------------

extern "C" void kernel_launch(void* const* d_in, const int* in_sizes, int n_in,
                              void* d_out, int out_size, void* d_ws, size_t ws_size,
                              hipStream_t stream) {
    const float* xnf = (const float*)d_in[0];
    const int* src = (const int*)d_in[1];
    const int* dst = (const int*)d_in[2];
    const float* l0w = (const float*)d_in[3];
    const float* l0b = (const float*)d_in[4];
    const float* fcw = (const float*)d_in[5];
    const float* al  = (const float*)d_in[6];
    const float* ar  = (const float*)d_in[7];
    const float* gb  = (const float*)d_in[8];
    const float* ow  = (const float*)d_in[9];
    const float* ob  = (const float*)d_in[10];
    float* out = (float*)d_out;
    const int N = in_sizes[0] / HID;
    const int E = in_sizes[1];
    const int NP = (N + (1 << PSHIFT) - 1) >> PSHIFT;  // 391 dst partitions
    const int C = (E + PCHUNK - 1) / PCHUNK;           // 391 chunks

    char* p = (char*)d_ws;
    auto alloc = [&](size_t bytes) {
        char* r = p;
        p += (bytes + 255) & ~(size_t)255;
        return r;
    };
    int* part    = (int*)alloc((size_t)E * 4);
    int* M       = (int*)alloc((size_t)NP * C * 4);
    int* BaseT   = (int*)alloc((size_t)C * 512 * 4);
    int* T       = (int*)alloc((size_t)NP * 4);
    int* poff    = (int*)alloc((size_t)(NP + 1) * 4);
    int* off     = (int*)alloc((size_t)(N + 1) * 4);
    int* csr     = (int*)alloc((size_t)E * 4);
    float* ha    = (float*)alloc((size_t)N * HID * 4);
    float* hb    = (float*)alloc((size_t)N * HID * 4);
    f16* pkA     = (f16*)alloc((size_t)N * 48 * 2);
    f16* pkB     = (f16*)alloc((size_t)N * 48 * 2);
    float* erA   = (float*)alloc((size_t)N * NH * 4);
    float* erB   = (float*)alloc((size_t)N * NH * 4);

    // CSR build (atomic-free partition, then per-partition LDS sort)
    hist2_kernel<<<C, 256, 0, stream>>>(dst, M, E, C, NP);
    base_scan_kernel<<<NP, 512, 0, stream>>>(M, BaseT, T, C, NP);
    scan_small_kernel<<<1, 512, 0, stream>>>(T, poff, NP);
    part_scatter_kernel<<<C, 256, 0, stream>>>(src, dst, BaseT, poff, part, E, NP);
    bucket_csr_kernel<<<NP, 256, 0, stream>>>(part, T, poff, csr, off, N, E);

    int nblk = (N + 255) / 256;
    int fblk = (N + 63) / 64;

    // h0 + transform(layer0)
    lin0tr_kernel<<<nblk, 256, 0, stream>>>(xnf, l0w, l0b, fcw, al, ar, ha, pkA, erA, N);

    // layer0 aggregate + transform(layer1)
    aggtr_kernel<<<fblk, 192, 0, stream>>>(pkA, erA, ha, off, csr, gb,
                                           fcw + (size_t)1 * HID * HID, al + HID, ar + HID,
                                           hb, pkB, erB, N);
    // layer1 aggregate + transform(layer2)
    aggtr_kernel<<<fblk, 192, 0, stream>>>(pkB, erB, hb, off, csr, gb + HID,
                                           fcw + (size_t)2 * HID * HID, al + 2 * HID, ar + 2 * HID,
                                           ha, pkA, erA, N);
    // layer2 aggregate + out GEMM (h3 never materialized)
    aggout_kernel<<<fblk, 192, 0, stream>>>(pkA, erA, ha, off, csr, gb + 2 * HID,
                                            ow, ob, out, N);
}

// Round 11
// 403.934 us; speedup vs baseline: 1.1019x; 1.1019x over previous
//
#include <hip/hip_runtime.h>
#include <math.h>

#define HID 36
#define NH 3
#define HD 12
#define BSHIFT 13   // src-bucket = src >> 13 (13 buckets for N=100000)
#define NBUCK 13
#define PSHIFT 8    // dst partition = dst >> 8 (256 dsts per partition)
#define PCHUNK 8192 // edges per chunk in partition pass
#define CSRCAP 4096 // LDS-staged csr entries per block (mean 2048, sigma 45)

typedef _Float16 f16;
typedef unsigned short u16;

// ---------------- CSR build: atomic-free two-level partition sort ----------

__global__ void hist2_kernel(const int* __restrict__ dst, int* __restrict__ M,
                             int E, int C, int np) {
    __shared__ int h[512];
    int t = threadIdx.x;
    int c = blockIdx.x;
    for (int i = t; i < 512; i += blockDim.x) h[i] = 0;
    __syncthreads();
    int i0 = c * PCHUNK;
    int i1 = min(i0 + PCHUNK, E);
    for (int i = i0 + t; i < i1; i += blockDim.x)
        atomicAdd(&h[dst[i] >> PSHIFT], 1);
    __syncthreads();
    for (int b = t; b < np; b += blockDim.x)
        M[(size_t)b * C + c] = h[b];
}

__global__ void base_scan_kernel(const int* __restrict__ M, int* __restrict__ BaseT,
                                 int* __restrict__ T, int C, int np) {
    __shared__ int tmp[512];
    int b = blockIdx.x;
    int t = threadIdx.x;
    int v = (t < C) ? M[(size_t)b * C + t] : 0;
    tmp[t] = v;
    __syncthreads();
    for (int ofs = 1; ofs < 512; ofs <<= 1) {
        int x = 0;
        if (t >= ofs) x = tmp[t - ofs];
        __syncthreads();
        tmp[t] += x;
        __syncthreads();
    }
    if (t < C) BaseT[(size_t)t * 512 + b] = tmp[t] - v;
    if (t == 511) T[b] = tmp[511];
}

__global__ void scan_small_kernel(const int* __restrict__ T, int* __restrict__ poff, int np) {
    __shared__ int tmp[512];
    int t = threadIdx.x;
    int v = (t < np) ? T[t] : 0;
    tmp[t] = v;
    __syncthreads();
    for (int ofs = 1; ofs < 512; ofs <<= 1) {
        int x = 0;
        if (t >= ofs) x = tmp[t - ofs];
        __syncthreads();
        tmp[t] += x;
        __syncthreads();
    }
    int excl = tmp[t] - v;
    if (t < np) poff[t] = excl;
    if (t == np - 1) poff[np] = excl + v;
}

__global__ void part_scatter_kernel(const int* __restrict__ src, const int* __restrict__ dst,
                                    const int* __restrict__ BaseT, const int* __restrict__ poff,
                                    int* __restrict__ part, int E, int np) {
    __shared__ int h[512];
    __shared__ int base[512];
    int t = threadIdx.x;
    int c = blockIdx.x;
    for (int i = t; i < 512; i += blockDim.x) h[i] = 0;
    for (int b = t; b < np; b += blockDim.x)
        base[b] = poff[b] + BaseT[(size_t)c * 512 + b];
    __syncthreads();
    int i0 = c * PCHUNK;
    int i1 = min(i0 + PCHUNK, E);
    for (int i = i0 + t; i < i1; i += blockDim.x) {
        int d = dst[i];
        int bin = d >> PSHIFT;
        int r = atomicAdd(&h[bin], 1);
        part[base[bin] + r] = (src[i] << PSHIFT) | (d & ((1 << PSHIFT) - 1));
    }
}

// one block per partition: LDS counting sort by (dst_local, src_bucket).
// csr entries = src*48; also emits per-(node,bucket) u16 counts.
__global__ void bucket_csr_kernel(const int* __restrict__ part, const int* __restrict__ T,
                                  const int* __restrict__ poff,
                                  int* __restrict__ csr, int* __restrict__ off,
                                  u16* __restrict__ counts, int n, int E) {
    __shared__ int cnt[256 * NBUCK];
    __shared__ int psum[256];
    int p = blockIdx.x;
    int t = threadIdx.x;
    int dbase = p << PSHIFT;
    int nd = min(256, n - dbase);
    int nc = nd * NBUCK;
    for (int i = t; i < nc; i += blockDim.x) cnt[i] = 0;
    __syncthreads();
    int cnt_p = T[p];
    int e0 = poff[p];
    const int* pp = part + e0;
    for (int i = t; i < cnt_p; i += blockDim.x) {
        int e = pp[i];
        atomicAdd(&cnt[(e & 255) * NBUCK + ((e >> PSHIFT) >> BSHIFT)], 1);
    }
    __syncthreads();
    int sum = 0;
    if (t < nd) {
        for (int k = 0; k < NBUCK; ++k) {
            int c = cnt[t * NBUCK + k];
            cnt[t * NBUCK + k] = sum;
            sum += c;
        }
    }
    psum[t] = (t < nd) ? sum : 0;
    __syncthreads();
    for (int ofs = 1; ofs < 256; ofs <<= 1) {
        int x = 0;
        if (t >= ofs) x = psum[t - ofs];
        __syncthreads();
        psum[t] += x;
        __syncthreads();
    }
    int dexcl = (t > 0) ? psum[t - 1] : 0;
    int start = e0 + dexcl;
    if (t < nd) {
        for (int k = 0; k < NBUCK; ++k) cnt[t * NBUCK + k] += start;
        off[dbase + t] = start;
    }
    __syncthreads();
    for (int i = t; i < cnt_p; i += blockDim.x) {
        int e = pp[i];
        int s = e >> PSHIFT;
        int idx = (e & 255) * NBUCK + (s >> BSHIFT);
        int pos = atomicAdd(&cnt[idx], 1);
        csr[pos] = s * 48;
    }
    __syncthreads();
    if (t < nd) {  // per-(node,bucket) u16 counts (cnt now holds segment ends)
        union { u16 cc[16]; uint4 q[2]; } u;
        int prev = start;
        for (int k = 0; k < NBUCK; ++k) {
            int end = cnt[t * NBUCK + k];
            u.cc[k] = (u16)(end - prev);
            prev = end;
        }
        u.cc[13] = 0; u.cc[14] = 0; u.cc[15] = 0;
        uint4* cp = (uint4*)(counts + (size_t)(dbase + t) * 16);
        cp[0] = u.q[0];
        cp[1] = u.q[1];
    }
    if (p == 0 && t == 0) off[n] = E;
}

// ---------------- fused node kernels ----------------

__device__ __forceinline__ void edge_accum(uint4 qa, uint4 qb, float ern,
                                           float& denom, float* acc) {
    union { uint4 q[2]; f16 hx[16]; } v;
    v.q[0] = qa;
    v.q[1] = qb;
    float e = (float)v.hx[12] + ern;
    e = (e >= 0.f) ? e : 0.2f * e;
    float w = __expf(e);
    denom += w;
#pragma unroll
    for (int k = 0; k < HD; ++k) acc[k] += w * (float)v.hx[k];
}

// h0 = x@W0+b0 ; feat = h0@FCW ; pack {feat12,el}x3 + er  (two reg-GEMMs)
__global__ void lin0tr_kernel(const float* __restrict__ x, const float* __restrict__ w0,
                              const float* __restrict__ b0, const float* __restrict__ fcw,
                              const float* __restrict__ al, const float* __restrict__ ar,
                              float* __restrict__ h, f16* __restrict__ packed,
                              float* __restrict__ er, int n) {
    __shared__ float W0[HID * HID];
    __shared__ float W1[HID * HID];
    __shared__ float Bs[HID], ALs[HID], ARs[HID];
    int t = threadIdx.x;
    for (int i = t; i < HID * HID; i += 256) { W0[i] = w0[i]; W1[i] = fcw[i]; }
    if (t < HID) { Bs[t] = b0[t]; ALs[t] = al[t]; ARs[t] = ar[t]; }
    __syncthreads();
    int node = blockIdx.x * 256 + t;
    if (node >= n) return;
    const float4* xp = (const float4*)(x + (size_t)node * HID);
    float h0[HID];
#pragma unroll
    for (int j = 0; j < HID; ++j) h0[j] = Bs[j];
#pragma unroll
    for (int kk = 0; kk < HID / 4; ++kk) {
        float4 xv = xp[kk];
        const float* w = &W0[(4 * kk) * HID];
#pragma unroll
        for (int j = 0; j < HID; ++j)
            h0[j] += xv.x * w[j] + xv.y * w[HID + j] + xv.z * w[2 * HID + j] + xv.w * w[3 * HID + j];
    }
    float* hp = h + (size_t)node * HID;
#pragma unroll
    for (int j = 0; j < HID; ++j) hp[j] = h0[j];
    float feat[HID];
#pragma unroll
    for (int j = 0; j < HID; ++j) feat[j] = 0.f;
#pragma unroll
    for (int k = 0; k < HID; ++k) {
        float hv = h0[k];
        const float* w = &W1[k * HID];
#pragma unroll
        for (int j = 0; j < HID; ++j) feat[j] += hv * w[j];
    }
    union { f16 hx[48]; uint4 q[6]; } u;
#pragma unroll
    for (int hh = 0; hh < NH; ++hh) {
        float sl = 0.f, sr = 0.f;
#pragma unroll
        for (int d = 0; d < HD; ++d) {
            sl += feat[hh * HD + d] * ALs[hh * HD + d];
            sr += feat[hh * HD + d] * ARs[hh * HD + d];
        }
#pragma unroll
        for (int d = 0; d < HD; ++d) u.hx[hh * 16 + d] = (f16)feat[hh * HD + d];
        u.hx[hh * 16 + 12] = (f16)sl;
        u.hx[hh * 16 + 13] = (f16)0.f;
        u.hx[hh * 16 + 14] = (f16)0.f;
        u.hx[hh * 16 + 15] = (f16)0.f;
        er[node * NH + hh] = sr;
    }
    uint4* prow = (uint4*)(packed + (size_t)node * 48);
#pragma unroll
    for (int q = 0; q < 6; ++q) prow[q] = u.q[q];
}

// fused: bucket-synchronized aggregate (csr staged in LDS, x2 unroll) ->
// hnext, then transform(l+1) via LDS exchange. 192 thr = 64 nodes x 3 heads.
__global__ void __launch_bounds__(192)
aggtr_kernel(const f16* __restrict__ packed_in, const float* __restrict__ er_in,
             const float* __restrict__ hcur, const u16* __restrict__ counts,
             const int* __restrict__ off, const int* __restrict__ csr,
             const float* __restrict__ bias, const float* __restrict__ wnext,
             const float* __restrict__ aln, const float* __restrict__ arn,
             float* __restrict__ hnext, f16* __restrict__ packed_out,
             float* __restrict__ er_out, int n) {
    __shared__ float Wsh[HID * HID];
    __shared__ float ALs[HID], ARs[HID];
    __shared__ int smbuf[CSRCAP];  // csr span during sweep; hsh afterwards
    int t = threadIdx.x;
    for (int i = t; i < HID * HID; i += 192) Wsh[i] = wnext[i];
    if (t < HID) { ALs[t] = aln[t]; ARs[t] = arn[t]; }
    int ln = t / 3, hh = t - ln * 3;
    int nb0 = blockIdx.x * 64;
    int node = nb0 + ln;
    bool active = (node < n);

    int e0 = off[nb0];
    int e1 = off[min(nb0 + 64, n)];
    int span = e1 - e0;
    for (int i = t; i < span && i < CSRCAP; i += 192) smbuf[i] = csr[e0 + i];

    int j = 0;
    float ern = 0.f;
    union { u16 cc[16]; uint4 q[2]; } u;
    u.q[0] = make_uint4(0, 0, 0, 0);
    u.q[1] = make_uint4(0, 0, 0, 0);
    if (active) {
        j = off[node] - e0;  // block-local csr index
        ern = er_in[node * NH + hh];
        const uint4* cp = (const uint4*)(counts + (size_t)node * 16);
        u.q[0] = cp[0];
        u.q[1] = cp[1];
    }
    const f16* pb = packed_in + hh * 16;
    __syncthreads();

    float denom = 0.f;
    float acc[HD];
#pragma unroll
    for (int k = 0; k < HD; ++k) acc[k] = 0.f;

    for (int kb = 0; kb < NBUCK; ++kb) {
        int c = u.cc[kb];
        for (; c >= 2; c -= 2, j += 2) {
            int o0 = (j < CSRCAP) ? smbuf[j] : csr[e0 + j];
            int o1 = (j + 1 < CSRCAP) ? smbuf[j + 1] : csr[e0 + j + 1];
            const uint4* r0 = (const uint4*)(pb + o0);
            const uint4* r1 = (const uint4*)(pb + o1);
            uint4 a0 = r0[0], b0 = r0[1];
            uint4 a1 = r1[0], b1 = r1[1];
            edge_accum(a0, b0, ern, denom, acc);
            edge_accum(a1, b1, ern, denom, acc);
        }
        if (c) {
            int o = (j < CSRCAP) ? smbuf[j] : csr[e0 + j];
            ++j;
            const uint4* r = (const uint4*)(pb + o);
            edge_accum(r[0], r[1], ern, denom, acc);
        }
        __syncthreads();
    }

    // epilogue: hnext = elu(acc/denom + hcur + bias); stage into hsh (=smbuf)
    float* hsh = (float*)smbuf;
    float v[HD];
#pragma unroll
    for (int k = 0; k < HD; ++k) v[k] = 0.f;
    if (active) {
        float inv = 1.f / fmaxf(denom, 1e-9f);
        int base = node * HID + hh * HD;
        const float4* hc = (const float4*)(hcur + base);
        float4 h0 = hc[0], h1 = hc[1], h2 = hc[2];
        float hres[HD] = {h0.x, h0.y, h0.z, h0.w, h1.x, h1.y, h1.z, h1.w, h2.x, h2.y, h2.z, h2.w};
#pragma unroll
        for (int k = 0; k < HD; ++k) {
            float x = acc[k] * inv + hres[k] + bias[hh * HD + k];
            v[k] = (x > 0.f) ? x : expm1f(x);
        }
        float4* hp = (float4*)(hnext + base);
        hp[0] = make_float4(v[0], v[1], v[2], v[3]);
        hp[1] = make_float4(v[4], v[5], v[6], v[7]);
        hp[2] = make_float4(v[8], v[9], v[10], v[11]);
    }
#pragma unroll
    for (int k = 0; k < HD; ++k) hsh[ln * 37 + hh * HD + k] = v[k];
    __syncthreads();

    // transform tail: feat12 = hsh[ln][:] @ Wsh[:, hh*12..], then el/er+pack
    float feat[HD];
#pragma unroll
    for (int d = 0; d < HD; ++d) feat[d] = 0.f;
    const float* hrow = &hsh[ln * 37];
#pragma unroll 4
    for (int k = 0; k < HID; ++k) {
        float hv = hrow[k];
        const float* w = &Wsh[k * HID + hh * HD];
#pragma unroll
        for (int d = 0; d < HD; ++d) feat[d] += hv * w[d];
    }
    if (!active) return;
    float sl = 0.f, sr = 0.f;
#pragma unroll
    for (int d = 0; d < HD; ++d) {
        sl += feat[d] * ALs[hh * HD + d];
        sr += feat[d] * ARs[hh * HD + d];
    }
    union { f16 hx[16]; uint4 q[2]; } o;
#pragma unroll
    for (int d = 0; d < HD; ++d) o.hx[d] = (f16)feat[d];
    o.hx[12] = (f16)sl;
    o.hx[13] = (f16)0.f; o.hx[14] = (f16)0.f; o.hx[15] = (f16)0.f;
    uint4* prow = (uint4*)(packed_out + (size_t)node * 48 + hh * 16);
    prow[0] = o.q[0];
    prow[1] = o.q[1];
    er_out[node * NH + hh] = sr;
}

// fused: aggregate(last layer) -> h3 (in-reg) -> out = h3@OW + ob
__global__ void __launch_bounds__(192)
aggout_kernel(const f16* __restrict__ packed_in, const float* __restrict__ er_in,
              const float* __restrict__ hcur, const u16* __restrict__ counts,
              const int* __restrict__ off, const int* __restrict__ csr,
              const float* __restrict__ bias, const float* __restrict__ ow,
              const float* __restrict__ ob, float* __restrict__ out, int n) {
    __shared__ float Wsh[HID * HID];
    __shared__ float OBs[HID];
    __shared__ int smbuf[CSRCAP];
    int t = threadIdx.x;
    for (int i = t; i < HID * HID; i += 192) Wsh[i] = ow[i];
    if (t < HID) OBs[t] = ob[t];
    int ln = t / 3, hh = t - ln * 3;
    int nb0 = blockIdx.x * 64;
    int node = nb0 + ln;
    bool active = (node < n);

    int e0 = off[nb0];
    int e1 = off[min(nb0 + 64, n)];
    int span = e1 - e0;
    for (int i = t; i < span && i < CSRCAP; i += 192) smbuf[i] = csr[e0 + i];

    int j = 0;
    float ern = 0.f;
    union { u16 cc[16]; uint4 q[2]; } u;
    u.q[0] = make_uint4(0, 0, 0, 0);
    u.q[1] = make_uint4(0, 0, 0, 0);
    if (active) {
        j = off[node] - e0;
        ern = er_in[node * NH + hh];
        const uint4* cp = (const uint4*)(counts + (size_t)node * 16);
        u.q[0] = cp[0];
        u.q[1] = cp[1];
    }
    const f16* pb = packed_in + hh * 16;
    __syncthreads();

    float denom = 0.f;
    float acc[HD];
#pragma unroll
    for (int k = 0; k < HD; ++k) acc[k] = 0.f;

    for (int kb = 0; kb < NBUCK; ++kb) {
        int c = u.cc[kb];
        for (; c >= 2; c -= 2, j += 2) {
            int o0 = (j < CSRCAP) ? smbuf[j] : csr[e0 + j];
            int o1 = (j + 1 < CSRCAP) ? smbuf[j + 1] : csr[e0 + j + 1];
            const uint4* r0 = (const uint4*)(pb + o0);
            const uint4* r1 = (const uint4*)(pb + o1);
            uint4 a0 = r0[0], b0 = r0[1];
            uint4 a1 = r1[0], b1 = r1[1];
            edge_accum(a0, b0, ern, denom, acc);
            edge_accum(a1, b1, ern, denom, acc);
        }
        if (c) {
            int o = (j < CSRCAP) ? smbuf[j] : csr[e0 + j];
            ++j;
            const uint4* r = (const uint4*)(pb + o);
            edge_accum(r[0], r[1], ern, denom, acc);
        }
        __syncthreads();
    }

    float* hsh = (float*)smbuf;
    float v[HD];
#pragma unroll
    for (int k = 0; k < HD; ++k) v[k] = 0.f;
    if (active) {
        float inv = 1.f / fmaxf(denom, 1e-9f);
        int base = node * HID + hh * HD;
        const float4* hc = (const float4*)(hcur + base);
        float4 h0 = hc[0], h1 = hc[1], h2 = hc[2];
        float hres[HD] = {h0.x, h0.y, h0.z, h0.w, h1.x, h1.y, h1.z, h1.w, h2.x, h2.y, h2.z, h2.w};
#pragma unroll
        for (int k = 0; k < HD; ++k) {
            float x = acc[k] * inv + hres[k] + bias[hh * HD + k];
            v[k] = (x > 0.f) ? x : expm1f(x);
        }
    }
#pragma unroll
    for (int k = 0; k < HD; ++k) hsh[ln * 37 + hh * HD + k] = v[k];
    __syncthreads();

    float feat[HD];
#pragma unroll
    for (int d = 0; d < HD; ++d) feat[d] = OBs[hh * HD + d];
    const float* hrow = &hsh[ln * 37];
#pragma unroll 4
    for (int k = 0; k < HID; ++k) {
        float hv = hrow[k];
        const float* w = &Wsh[k * HID + hh * HD];
#pragma unroll
        for (int d = 0; d < HD; ++d) feat[d] += hv * w[d];
    }
    if (!active) return;
    float4* op = (float4*)(out + (size_t)node * HID + hh * HD);
    op[0] = make_float4(feat[0], feat[1], feat[2], feat[3]);
    op[1] = make_float4(feat[4], feat[5], feat[6], feat[7]);
    op[2] = make_float4(feat[8], feat[9], feat[10], feat[11]);
}

// ---------------- launch ----------------

extern "C" void kernel_launch(void* const* d_in, const int* in_sizes, int n_in,
                              void* d_out, int out_size, void* d_ws, size_t ws_size,
                              hipStream_t stream) {
    const float* xnf = (const float*)d_in[0];
    const int* src = (const int*)d_in[1];
    const int* dst = (const int*)d_in[2];
    const float* l0w = (const float*)d_in[3];
    const float* l0b = (const float*)d_in[4];
    const float* fcw = (const float*)d_in[5];
    const float* al  = (const float*)d_in[6];
    const float* ar  = (const float*)d_in[7];
    const float* gb  = (const float*)d_in[8];
    const float* ow  = (const float*)d_in[9];
    const float* ob  = (const float*)d_in[10];
    float* out = (float*)d_out;
    const int N = in_sizes[0] / HID;
    const int E = in_sizes[1];
    const int NP = (N + (1 << PSHIFT) - 1) >> PSHIFT;  // 391 dst partitions
    const int C = (E + PCHUNK - 1) / PCHUNK;           // 391 chunks

    char* p = (char*)d_ws;
    auto alloc = [&](size_t bytes) {
        char* r = p;
        p += (bytes + 255) & ~(size_t)255;
        return r;
    };
    int* part    = (int*)alloc((size_t)E * 4);
    int* M       = (int*)alloc((size_t)NP * C * 4);
    int* BaseT   = (int*)alloc((size_t)C * 512 * 4);
    int* T       = (int*)alloc((size_t)NP * 4);
    int* poff    = (int*)alloc((size_t)(NP + 1) * 4);
    int* off     = (int*)alloc((size_t)(N + 1) * 4);
    int* csr     = (int*)alloc((size_t)E * 4);
    u16* counts  = (u16*)alloc((size_t)N * 16 * 2);
    float* ha    = (float*)alloc((size_t)N * HID * 4);
    float* hb    = (float*)alloc((size_t)N * HID * 4);
    f16* pkA     = (f16*)alloc((size_t)N * 48 * 2);
    f16* pkB     = (f16*)alloc((size_t)N * 48 * 2);
    float* erA   = (float*)alloc((size_t)N * NH * 4);
    float* erB   = (float*)alloc((size_t)N * NH * 4);

    // CSR build (atomic-free partition, then per-partition LDS sort)
    hist2_kernel<<<C, 256, 0, stream>>>(dst, M, E, C, NP);
    base_scan_kernel<<<NP, 512, 0, stream>>>(M, BaseT, T, C, NP);
    scan_small_kernel<<<1, 512, 0, stream>>>(T, poff, NP);
    part_scatter_kernel<<<C, 256, 0, stream>>>(src, dst, BaseT, poff, part, E, NP);
    bucket_csr_kernel<<<NP, 256, 0, stream>>>(part, T, poff, csr, off, counts, N, E);

    int nblk = (N + 255) / 256;
    int fblk = (N + 63) / 64;

    // h0 + transform(layer0)
    lin0tr_kernel<<<nblk, 256, 0, stream>>>(xnf, l0w, l0b, fcw, al, ar, ha, pkA, erA, N);

    // layer0 aggregate + transform(layer1)
    aggtr_kernel<<<fblk, 192, 0, stream>>>(pkA, erA, ha, counts, off, csr, gb,
                                           fcw + (size_t)1 * HID * HID, al + HID, ar + HID,
                                           hb, pkB, erB, N);
    // layer1 aggregate + transform(layer2)
    aggtr_kernel<<<fblk, 192, 0, stream>>>(pkB, erB, hb, counts, off, csr, gb + HID,
                                           fcw + (size_t)2 * HID * HID, al + 2 * HID, ar + 2 * HID,
                                           ha, pkA, erA, N);
    // layer2 aggregate + out GEMM (h3 never materialized)
    aggout_kernel<<<fblk, 192, 0, stream>>>(pkA, erA, ha, counts, off, csr, gb + 2 * HID,
                                            ow, ob, out, N);
}